// Round 3
// baseline (387.299 us; speedup 1.0000x reference)
//
#include <hip/hip_runtime.h>
#include <cstdint>

constexpr int B = 32, C = 256, H = 56, W = 56;
constexpr int HW = H * W;          // 3136
constexpr int WORDS = C / 32;      // 8 u32 words per pixel
constexpr int TAPS = 9;
constexpr int WPC = TAPS * WORDS;  // 72 words of weights per output channel
constexpr int PH = H + 2, PW = W + 2, PHW = PH * PW;  // padded 58x58 = 3364

// ---------------------------------------------------------------------------
// Pack x signs into zero-padded buffer: px[b][ph][pw][wd], pad ring = 0.
// Thread map (b, wd, pp) with pp fastest -> channel-plane reads are contiguous
// across the wave. Pad threads write 0 every launch (ws is re-poisoned).
// ---------------------------------------------------------------------------
__global__ __launch_bounds__(256) void pack_x_kernel(const float* __restrict__ x,
                                                     uint32_t* __restrict__ px) {
    int idx = blockIdx.x * 256 + threadIdx.x;   // B*WORDS*PHW = 861184 exact
    int pp = idx % PHW;
    int r = idx / PHW;
    int wd = r % WORDS;
    int b = r / WORDS;
    int ph = pp / PW, pwp = pp - ph * PW;
    uint32_t bits = 0;
    if (ph >= 1 && ph <= H && pwp >= 1 && pwp <= W) {
        const float* xp = x + ((size_t)b * C + wd * 32) * HW + (size_t)(ph - 1) * W + (pwp - 1);
        #pragma unroll
        for (int i = 0; i < 32; ++i)
            bits |= (xp[(size_t)i * HW] < 0.0f ? (1u << i) : 0u);
    }
    px[((size_t)(b * PH + ph) * PW + pwp) * WORDS + wd] = bits;
}

// ---------------------------------------------------------------------------
// Pack w signs via ballot: one wave per (co, tap, 64-channel chunk).
// Each lane loads one weight; __ballot packs 64 sign bits -> 2 words.
// pw[co][tap][wd], bit i of word wd = (w[co][wd*32+i][tap] < 0).
// ---------------------------------------------------------------------------
__global__ __launch_bounds__(256) void pack_w_kernel(const float* __restrict__ wt,
                                                     uint32_t* __restrict__ pw) {
    int gid = blockIdx.x * 256 + threadIdx.x;   // C*9*4*64 = 589824 exact
    int lane = gid & 63;
    int wv = gid >> 6;            // (co*9 + tap)*4 + pr
    int pr = wv & 3;
    int ct = wv >> 2;
    int tap = ct % 9;
    int co = ct / 9;
    int ci = pr * 64 + lane;
    float v = wt[((size_t)co * C + ci) * TAPS + tap];
    unsigned long long m = __ballot(v < 0.0f);
    if (lane == 0) {
        pw[(size_t)co * WPC + tap * WORDS + pr * 2]     = (uint32_t)m;
        pw[(size_t)co * WPC + tap * WORDS + pr * 2 + 1] = (uint32_t)(m >> 32);
    }
}

// ---------------------------------------------------------------------------
// basec[cls][co] = 256*nvalid(cls) + 2*sum_{t invalid in cls} popc(w[co][t]) + bias[co]
// With zero pad-words, out = basec - 2*total_all exactly, including borders.
// cls = clsh*3+clsw; clsh/clsw in {0:lo-edge, 1:interior, 2:hi-edge}.
// ---------------------------------------------------------------------------
__global__ __launch_bounds__(256) void basec_kernel(const uint32_t* __restrict__ pw,
                                                    const float* __restrict__ bias,
                                                    float* __restrict__ basec) {
    int idx = blockIdx.x * 256 + threadIdx.x;   // 9*C = 2304 exact
    int co = idx & (C - 1);
    int cls = idx >> 8;
    int clsh = cls / 3, clsw = cls - clsh * 3;
    int nvalid = 0, invsum = 0;
    #pragma unroll
    for (int t = 0; t < TAPS; ++t) {
        int dh = t / 3 - 1, dw = t % 3 - 1;
        bool vh = !((dh == -1 && clsh == 0) || (dh == 1 && clsh == 2));
        bool vw = !((dw == -1 && clsw == 0) || (dw == 1 && clsw == 2));
        if (vh && vw) {
            ++nvalid;
        } else {
            int p = 0;
            #pragma unroll
            for (int k = 0; k < WORDS; ++k)
                p += __popc(pw[(size_t)co * WPC + t * WORDS + k]);
            invsum += p;
        }
    }
    basec[idx] = (float)(256 * nvalid + 2 * invsum) + bias[co];
}

// ---------------------------------------------------------------------------
// Main conv, border-exact via basec. Block = 4 waves; wave wid owns the
// 64-co chunk cobase=wid*64 (readfirstlane keeps weight addresses scalar ->
// s_load / SMEM pipe). Lane = one of 64 consecutive hw. Per co:
// 72x (v_xor + v_bcnt-acc) + 3 adds + cvt + fma + L1 basec load + store.
// ---------------------------------------------------------------------------
__global__ __launch_bounds__(256) void bconv_kernel(const uint32_t* __restrict__ px,
                                                    const uint32_t* __restrict__ pw,
                                                    const float* __restrict__ basec,
                                                    float* __restrict__ out) {
    const int lane = threadIdx.x & 63;
    const int wid = __builtin_amdgcn_readfirstlane(threadIdx.x >> 6);
    const int hw = blockIdx.x * 64 + lane;      // 3136 = 49*64 exact
    const int b = blockIdx.y;
    const int h = hw / W;
    const int w = hw - h * W;

    uint32_t pxr[TAPS][WORDS];
    #pragma unroll
    for (int t = 0; t < TAPS; ++t) {
        const int dh = t / 3 - 1, dw = t - (t / 3) * 3 - 1;
        const uint4* p = reinterpret_cast<const uint4*>(
            px + ((size_t)(b * PH + (h + 1 + dh)) * PW + (w + 1 + dw)) * WORDS);
        uint4 a = p[0], q = p[1];
        pxr[t][0] = a.x; pxr[t][1] = a.y; pxr[t][2] = a.z; pxr[t][3] = a.w;
        pxr[t][4] = q.x; pxr[t][5] = q.y; pxr[t][6] = q.z; pxr[t][7] = q.w;
    }

    const int clsh = (h == 0) ? 0 : ((h == H - 1) ? 2 : 1);
    const int clsw = (w == 0) ? 0 : ((w == W - 1) ? 2 : 1);
    const int cobase = wid * 64;
    const float* bp = basec + (clsh * 3 + clsw) * C + cobase;   // per-lane, L1-hot
    const uint32_t* wbase = pw + (size_t)cobase * WPC;           // scalar
    float* op = out + ((size_t)b * C + cobase) * HW + hw;

    #pragma unroll 1
    for (int j = 0; j < 64; ++j) {
        const uint32_t* wr = wbase + (size_t)j * WPC;            // wave-uniform
        uint32_t a0 = 0, a1 = 0, a2 = 0, a3 = 0;
        #pragma unroll
        for (int t = 0; t < TAPS; ++t) {
            a0 += __popc(pxr[t][0] ^ wr[t * WORDS + 0]);
            a1 += __popc(pxr[t][1] ^ wr[t * WORDS + 1]);
            a2 += __popc(pxr[t][2] ^ wr[t * WORDS + 2]);
            a3 += __popc(pxr[t][3] ^ wr[t * WORDS + 3]);
            a0 += __popc(pxr[t][4] ^ wr[t * WORDS + 4]);
            a1 += __popc(pxr[t][5] ^ wr[t * WORDS + 5]);
            a2 += __popc(pxr[t][6] ^ wr[t * WORDS + 6]);
            a3 += __popc(pxr[t][7] ^ wr[t * WORDS + 7]);
        }
        uint32_t total = (a0 + a1) + (a2 + a3);
        op[(size_t)j * HW] = fmaf(-2.0f, (float)(int)total, bp[j]);
    }
}

extern "C" void kernel_launch(void* const* d_in, const int* in_sizes, int n_in,
                              void* d_out, int out_size, void* d_ws, size_t ws_size,
                              hipStream_t stream) {
    const float* x = (const float*)d_in[0];
    const float* wt = (const float*)d_in[1];
    const float* bias = (const float*)d_in[2];
    float* out = (float*)d_out;

    uint32_t* px = (uint32_t*)d_ws;                       // 32*58*58*8*4 = 3,444,736 B
    uint32_t* pw = px + (size_t)B * PHW * WORDS;          // + 73,728 B
    float* basec = (float*)(pw + (size_t)C * WPC);        // + 9*256*4 = 9,216 B

    pack_x_kernel<<<(B * WORDS * PHW) / 256, 256, 0, stream>>>(x, px);
    pack_w_kernel<<<(C * TAPS * 4 * 64) / 256, 256, 0, stream>>>(wt, pw);
    basec_kernel<<<(9 * C) / 256, 256, 0, stream>>>(pw, bias, basec);

    dim3 grid(HW / 64, B);
    bconv_kernel<<<grid, 256, 0, stream>>>(px, pw, basec, out);
}